// Round 1
// baseline (3921.640 us; speedup 1.0000x reference)
//
#include <hip/hip_runtime.h>

// ---------------- problem constants ----------------
#define Hd   512            // hidden
#define Fd   128            // features
#define Td   512            // seq len
#define Bd   512            // batch
#define TG   64             // gate rows per wg (4 gates x 16 hidden)
#define BG   64             // batches per group
#define WPG  32             // wgs per group
#define LDH  520            // padded batch-row stride of h tile in LDS (bf16 elems)
#define LDG  68             // padded batch-stride of gate staging (f32 elems)

typedef __bf16 bf16x8 __attribute__((ext_vector_type(8)));
typedef float  f32x4  __attribute__((ext_vector_type(4)));
typedef unsigned int u32x4 __attribute__((ext_vector_type(4)));
typedef unsigned int u32x2 __attribute__((ext_vector_type(2)));

__device__ __forceinline__ unsigned short f2bf(float x) {
    unsigned u = __float_as_uint(x);
    unsigned r = (u + 0x7fffu + ((u >> 16) & 1u)) >> 16;   // RNE
    return (unsigned short)r;
}
__device__ __forceinline__ float sigm(float x) {
    return 1.0f / (1.0f + __expf(-x));
}
__device__ __forceinline__ float tanh_fast(float x) {
    float xc = fminf(fmaxf(x, -15.f), 15.f);
    float e  = __expf(2.f * xc);
    return (e - 1.f) / (e + 1.f);
}
// pack 8 consecutive f32 -> bf16x8 with the same RNE as the old LDS staging
__device__ __forceinline__ bf16x8 pack8(const float* p) {
    float4 a = *(const float4*)p;
    float4 b = *(const float4*)(p + 4);
    union { unsigned short u[8]; bf16x8 v; } r;
    r.u[0] = f2bf(a.x); r.u[1] = f2bf(a.y); r.u[2] = f2bf(a.z); r.u[3] = f2bf(a.w);
    r.u[4] = f2bf(b.x); r.u[5] = f2bf(b.y); r.u[6] = f2bf(b.z); r.u[7] = f2bf(b.w);
    return r.v;
}

// Persistent LSTM. 256 wgs x 256 threads (1 wg/CU; all co-resident).
// Group g = blockIdx&7 owns batches [g*64, g*64+64); wg r = blockIdx>>3 owns
// hidden units [r*16, r*16+16).
// h exchange: sc1 write-through stores + vmcnt(0) drain -> RELAXED flag.
// x-projection for step t+1 is computed inside the barrier-skew window.
// NEW this round: W_hh / W_ih MFMA A-fragments live in REGISTERS (loaded once,
// 160 VGPR/lane) instead of LDS -> per-step LDS b128 reads halve (256 -> 128
// per CU); occupancy is grid-limited (1 wave/SIMD) so the VGPR cost is free.
__global__ __launch_bounds__(256, 1) void lstm_persist(
    const float* __restrict__ X,     const float* __restrict__ W_ih,
    const float* __restrict__ W_hh,  const float* __restrict__ b_ih,
    const float* __restrict__ b_hh,  const float* __restrict__ W_out,
    const float* __restrict__ b_out, float* __restrict__ out,
    unsigned short* __restrict__ hbuf,   // [2][Bd][Hd] bf16 bits (zeroed)
    unsigned int*  __restrict__ bar)     // 8 counters, 128B apart (zeroed)
{
    extern __shared__ char smem[];
    unsigned short* htile = (unsigned short*)smem;              // 64*520*2 = 66560 B
    float*          gsum  = (float*)smem;                       // overlays htile
    float*          biasl = (float*)(smem + TG * LDH * 2);
    float*          hpart = biasl + TG;

    const int tid = threadIdx.x;
    const int gid = blockIdx.x;
    const int grp = gid & 7;
    const int r   = gid >> 3;
    const int bb  = grp * BG;
    const int jb  = r * 16;

    // ---- wave/tile constants ----
    const int lane = tid & 63, wid = tid >> 6;
    const int m16  = lane & 15, quad = lane >> 4;
    const int gr0  = (wid & 1) * 32;          // gate-row offset (local)
    const int bt0  = (wid >> 1) * 32;         // batch offset (in group)
    const int brow0 = bb + bt0 + m16;
    const int brow1 = brow0 + 16;
    const unsigned short* hl0 = htile + (bt0 + m16) * LDH + quad * 8;
    const unsigned short* hl1 = hl0 + 16 * LDH;

    // ---- W fragments into registers (one-time; replaces LDS W slice) ----
    // lane (m16, quad) holds A[row = gr0(+16) + m16][k = ks*32 + quad*8 .. +8]
    bf16x8 wh0[16], wh1[16], wx0[4], wx1[4];
    {
        const int lr0 = gr0 + m16, lr1 = lr0 + 16;
        const int gw0 = ((lr0 >> 4) * Hd) + jb + (lr0 & 15);
        const int gw1 = ((lr1 >> 4) * Hd) + jb + (lr1 & 15);
        const float* ph0 = W_hh + (size_t)gw0 * Hd + quad * 8;
        const float* ph1 = W_hh + (size_t)gw1 * Hd + quad * 8;
        const float* px0 = W_ih + (size_t)gw0 * Fd + quad * 8;
        const float* px1 = W_ih + (size_t)gw1 * Fd + quad * 8;
#pragma unroll
        for (int ks = 0; ks < 16; ++ks) {
            wh0[ks] = pack8(ph0 + ks * 32);
            wh1[ks] = pack8(ph1 + ks * 32);
        }
#pragma unroll
        for (int ks = 0; ks < 4; ++ks) {
            wx0[ks] = pack8(px0 + ks * 32);
            wx1[ks] = pack8(px1 + ks * 32);
        }
    }
    if (tid < TG) {
        int grow = ((tid >> 4) * Hd) + jb + (tid & 15);
        biasl[tid] = b_ih[grow] + b_hh[grow];
    }
    __syncthreads();

    // elementwise mapping
    const int eb  = tid & 63;
    const int jjb = (tid >> 6) << 2;
    float wout[4];
#pragma unroll
    for (int u = 0; u < 4; ++u) wout[u] = W_out[jb + jjb + u];
    const float bo = b_out[0];
    float cst[4] = {0.f, 0.f, 0.f, 0.f};

    unsigned int* mybar = bar + grp * 32;
    unsigned short* hw_lds = htile + (size_t)(tid >> 6) * LDH + (tid & 63) * 8;

    f32x4 acc00, acc01, acc10, acc11;
    const float* xp0 = X + (size_t)brow0 * (Td * Fd) + quad * 8;
    const float* xp1 = X + (size_t)brow1 * (Td * Fd) + quad * 8;

    // x-projection MFMAs for one timestep (reads current xp0/xp1)
    auto do_xpart = [&]() {
#pragma unroll
        for (int ks = 0; ks < 4; ++ks) {
            float4 xa = *(const float4*)(xp0 + ks * 32);
            float4 xb = *(const float4*)(xp0 + ks * 32 + 4);
            float4 ya = *(const float4*)(xp1 + ks * 32);
            float4 yb = *(const float4*)(xp1 + ks * 32 + 4);
            bf16x8 b0, b1;
            b0[0]=(__bf16)xa.x; b0[1]=(__bf16)xa.y; b0[2]=(__bf16)xa.z; b0[3]=(__bf16)xa.w;
            b0[4]=(__bf16)xb.x; b0[5]=(__bf16)xb.y; b0[6]=(__bf16)xb.z; b0[7]=(__bf16)xb.w;
            b1[0]=(__bf16)ya.x; b1[1]=(__bf16)ya.y; b1[2]=(__bf16)ya.z; b1[3]=(__bf16)ya.w;
            b1[4]=(__bf16)yb.x; b1[5]=(__bf16)yb.y; b1[6]=(__bf16)yb.z; b1[7]=(__bf16)yb.w;
            acc00 = __builtin_amdgcn_mfma_f32_16x16x32_bf16(wx0[ks], b0, acc00, 0, 0, 0);
            acc01 = __builtin_amdgcn_mfma_f32_16x16x32_bf16(wx0[ks], b1, acc01, 0, 0, 0);
            acc10 = __builtin_amdgcn_mfma_f32_16x16x32_bf16(wx1[ks], b0, acc10, 0, 0, 0);
            acc11 = __builtin_amdgcn_mfma_f32_16x16x32_bf16(wx1[ks], b1, acc11, 0, 0, 0);
        }
    };

    // prologue: x-part for t=0
    acc00 = f32x4{0.f,0.f,0.f,0.f}; acc01 = f32x4{0.f,0.f,0.f,0.f};
    acc10 = f32x4{0.f,0.f,0.f,0.f}; acc11 = f32x4{0.f,0.f,0.f,0.f};
    do_xpart();

    for (int t = 0; t < Td; ++t) {
        // ---- poll: all wgs have stored h(t-1) ----
        if (t > 0 && tid == 0) {
            unsigned tgt = (unsigned)t * WPG;
            while (__hip_atomic_load(mybar, __ATOMIC_RELAXED, __HIP_MEMORY_SCOPE_AGENT) < tgt)
                __builtin_amdgcn_s_sleep(2);
        }
        __syncthreads();                                   // A: flag seen; gsum/hpart free

        const unsigned short* hprev = hbuf + (size_t)((t & 1) ^ 1) * (Bd * Hd);

        // ---- load group h tile (64 KB) with sc1 and stage to LDS ----
        u32x4 hv0,hv1,hv2,hv3,hv4,hv5,hv6,hv7,hv8,hv9,hv10,hv11,hv12,hv13,hv14,hv15;
        {
            const unsigned short* p0 =
                hprev + (size_t)(bb + (tid >> 6)) * Hd + (tid & 63) * 8;
            const unsigned short* b0p = p0 + 1 * 2048;
            const unsigned short* b1p = p0 + 3 * 2048;
            const unsigned short* b2p = p0 + 5 * 2048;
            const unsigned short* b3p = p0 + 7 * 2048;
            const unsigned short* b4p = p0 + 9 * 2048;
            const unsigned short* b5p = p0 + 11 * 2048;
            const unsigned short* b6p = p0 + 13 * 2048;
            const unsigned short* b7p = p0 + 15 * 2048;
            asm volatile(
                "global_load_dwordx4 %0,  %16, off offset:-4096 sc1\n\t"
                "global_load_dwordx4 %1,  %16, off sc1\n\t"
                "global_load_dwordx4 %2,  %17, off offset:-4096 sc1\n\t"
                "global_load_dwordx4 %3,  %17, off sc1\n\t"
                "global_load_dwordx4 %4,  %18, off offset:-4096 sc1\n\t"
                "global_load_dwordx4 %5,  %18, off sc1\n\t"
                "global_load_dwordx4 %6,  %19, off offset:-4096 sc1\n\t"
                "global_load_dwordx4 %7,  %19, off sc1\n\t"
                "global_load_dwordx4 %8,  %20, off offset:-4096 sc1\n\t"
                "global_load_dwordx4 %9,  %20, off sc1\n\t"
                "global_load_dwordx4 %10, %21, off offset:-4096 sc1\n\t"
                "global_load_dwordx4 %11, %21, off sc1\n\t"
                "global_load_dwordx4 %12, %22, off offset:-4096 sc1\n\t"
                "global_load_dwordx4 %13, %22, off sc1\n\t"
                "global_load_dwordx4 %14, %23, off offset:-4096 sc1\n\t"
                "global_load_dwordx4 %15, %23, off sc1\n\t"
                "s_waitcnt vmcnt(0)"
                : "=&v"(hv0), "=&v"(hv1), "=&v"(hv2), "=&v"(hv3),
                  "=&v"(hv4), "=&v"(hv5), "=&v"(hv6), "=&v"(hv7),
                  "=&v"(hv8), "=&v"(hv9), "=&v"(hv10), "=&v"(hv11),
                  "=&v"(hv12), "=&v"(hv13), "=&v"(hv14), "=&v"(hv15)
                : "v"(b0p), "v"(b1p), "v"(b2p), "v"(b3p),
                  "v"(b4p), "v"(b5p), "v"(b6p), "v"(b7p)
                : "memory");
        }
        *(u32x4*)(hw_lds + 0 * 2080)  = hv0;  *(u32x4*)(hw_lds + 1 * 2080)  = hv1;
        *(u32x4*)(hw_lds + 2 * 2080)  = hv2;  *(u32x4*)(hw_lds + 3 * 2080)  = hv3;
        *(u32x4*)(hw_lds + 4 * 2080)  = hv4;  *(u32x4*)(hw_lds + 5 * 2080)  = hv5;
        *(u32x4*)(hw_lds + 6 * 2080)  = hv6;  *(u32x4*)(hw_lds + 7 * 2080)  = hv7;
        *(u32x4*)(hw_lds + 8 * 2080)  = hv8;  *(u32x4*)(hw_lds + 9 * 2080)  = hv9;
        *(u32x4*)(hw_lds + 10 * 2080) = hv10; *(u32x4*)(hw_lds + 11 * 2080) = hv11;
        *(u32x4*)(hw_lds + 12 * 2080) = hv12; *(u32x4*)(hw_lds + 13 * 2080) = hv13;
        *(u32x4*)(hw_lds + 14 * 2080) = hv14; *(u32x4*)(hw_lds + 15 * 2080) = hv15;
        __syncthreads();                                   // B: htile ready

        // ---- h part (K = 0..511): A from registers, B from LDS ----
#pragma unroll
        for (int ks = 0; ks < 16; ++ks) {
            bf16x8 b0 = *(const bf16x8*)(hl0 + ks * 32);
            bf16x8 b1 = *(const bf16x8*)(hl1 + ks * 32);
            acc00 = __builtin_amdgcn_mfma_f32_16x16x32_bf16(wh0[ks], b0, acc00, 0, 0, 0);
            acc01 = __builtin_amdgcn_mfma_f32_16x16x32_bf16(wh0[ks], b1, acc01, 0, 0, 0);
            acc10 = __builtin_amdgcn_mfma_f32_16x16x32_bf16(wh1[ks], b0, acc10, 0, 0, 0);
            acc11 = __builtin_amdgcn_mfma_f32_16x16x32_bf16(wh1[ks], b1, acc11, 0, 0, 0);
        }
        __syncthreads();                                   // C: htile free

        // ---- gate preacts to LDS (C-layout: row = quad*4+v, col = lane&15) ----
        {
            const int row = gr0 + (quad << 2);
            const int col = bt0 + m16;
            float* g00 = gsum + row * LDG + col;
            float* g10 = gsum + (row + 16) * LDG + col;
#pragma unroll
            for (int v = 0; v < 4; ++v) {
                g00[v * LDG]      = acc00[v];
                g00[v * LDG + 16] = acc01[v];
                g10[v * LDG]      = acc10[v];
                g10[v * LDG + 16] = acc11[v];
            }
        }
        __syncthreads();                                   // D: gsum ready

        // ---- gate math; c in regs; h -> global via sc1 write-through ----
        float part = 0.f;
        unsigned short hvb[4];
#pragma unroll
        for (int u = 0; u < 4; ++u) {
            int jj = jjb + u;
            float pi = gsum[jj * LDG + eb]        + biasl[jj];
            float pf = gsum[(16 + jj) * LDG + eb] + biasl[16 + jj];
            float pg = gsum[(32 + jj) * LDG + eb] + biasl[32 + jj];
            float po = gsum[(48 + jj) * LDG + eb] + biasl[48 + jj];
            float ii = sigm(pi), ff = sigm(pf);
            float gg = tanh_fast(pg), oo = sigm(po);
            float c  = ff * cst[u] + ii * gg;
            cst[u]   = c;
            float h  = oo * tanh_fast(c);
            hvb[u]   = f2bf(h);
            part    += h * wout[u];
        }
        {
            u32x2 hd2;
            hd2[0] = (unsigned)hvb[0] | ((unsigned)hvb[1] << 16);
            hd2[1] = (unsigned)hvb[2] | ((unsigned)hvb[3] << 16);
            unsigned short* hwp =
                hbuf + (size_t)(t & 1) * (Bd * Hd) + (size_t)(bb + eb) * Hd + jb + jjb;
            asm volatile("global_store_dwordx2 %0, %1, off sc1"
                         :: "v"(hwp), "v"(hd2) : "memory");
            asm volatile("s_waitcnt vmcnt(0)" ::: "memory");  // durable at coherence point
        }
        // ---- flag: RELAXED (ordering provided by the vmcnt(0) drain above) ----
        if (tid == 0)
            __hip_atomic_fetch_add(mybar, 1u, __ATOMIC_RELAXED, __HIP_MEMORY_SCOPE_AGENT);

        hpart[tid] = part;

        // ---- overlap barrier skew: x-part for t+1 ----
        acc00 = f32x4{0.f,0.f,0.f,0.f}; acc01 = f32x4{0.f,0.f,0.f,0.f};
        acc10 = f32x4{0.f,0.f,0.f,0.f}; acc11 = f32x4{0.f,0.f,0.f,0.f};
        if (t + 1 < Td) {
            xp0 += Fd; xp1 += Fd;
            do_xpart();
        }

        __syncthreads();                                   // E: hpart ready
        if (tid < 64) {
            float s = hpart[tid] + hpart[tid + 64] + hpart[tid + 128] + hpart[tid + 192];
            if (r == 0) s += bo;
            atomicAdd(out + (size_t)(bb + tid) * Td + t, s);
        }
    }
}

extern "C" void kernel_launch(void* const* d_in, const int* in_sizes, int n_in,
                              void* d_out, int out_size, void* d_ws, size_t ws_size,
                              hipStream_t stream) {
    const float* X     = (const float*)d_in[0];
    const float* W_ih  = (const float*)d_in[1];
    const float* W_hh  = (const float*)d_in[2];
    const float* b_ih  = (const float*)d_in[3];
    const float* b_hh  = (const float*)d_in[4];
    const float* W_out = (const float*)d_in[5];
    const float* b_out = (const float*)d_in[6];
    float* out = (float*)d_out;

    unsigned short* hbuf = (unsigned short*)d_ws;                 // 2*Bd*Hd bf16 = 1 MiB
    unsigned int*   bar  = (unsigned int*)((char*)d_ws + 2u * Bd * Hd * 2u);

    hipMemsetAsync(d_ws, 0, 2u * Bd * Hd * 2u + 4096u, stream);
    hipMemsetAsync(d_out, 0, (size_t)out_size * sizeof(float), stream);

    const size_t smem = (size_t)TG * LDH * 2      // htile/gsum    66560
                      + TG * 4 + 256 * 4;         // bias + hpart   1280  => 67840
    (void)hipFuncSetAttribute((const void*)lstm_persist,
                              hipFuncAttributeMaxDynamicSharedMemorySize, (int)smem);

    lstm_persist<<<dim3(256), dim3(256), smem, stream>>>(
        X, W_ih, W_hh, b_ih, b_hh, W_out, b_out, out, hbuf, bar);
}

// Round 2
// 3424.795 us; speedup vs baseline: 1.1451x; 1.1451x over previous
//
#include <hip/hip_runtime.h>

// ---------------- problem constants ----------------
#define Hd   512            // hidden
#define Fd   128            // features
#define Td   512            // seq len
#define Bd   512            // batch
#define TG   64             // gate rows per wg (4 gates x 16 hidden)
#define BG   64             // batches per group
#define WPG  32             // wgs per group
#define LDH  520            // padded batch-row stride of h tile in LDS (bf16 elems)
#define LDG  68             // padded batch-stride of gate staging (f32 elems)

typedef __bf16 bf16x8 __attribute__((ext_vector_type(8)));
typedef float  f32x4  __attribute__((ext_vector_type(4)));
typedef unsigned int u32x4 __attribute__((ext_vector_type(4)));
typedef unsigned int u32x2 __attribute__((ext_vector_type(2)));

__device__ __forceinline__ unsigned short f2bf(float x) {
    unsigned u = __float_as_uint(x);
    unsigned r = (u + 0x7fffu + ((u >> 16) & 1u)) >> 16;   // RNE
    return (unsigned short)r;
}
__device__ __forceinline__ float sigm(float x) {
    return 1.0f / (1.0f + __expf(-x));
}
__device__ __forceinline__ float tanh_fast(float x) {
    float xc = fminf(fmaxf(x, -15.f), 15.f);
    float e  = __expf(2.f * xc);
    return (e - 1.f) / (e + 1.f);
}
// pack 8 consecutive f32 -> bf16x8 with the same RNE as LDS staging did
__device__ __forceinline__ bf16x8 pack8(const float* p) {
    float4 a = *(const float4*)p;
    float4 b = *(const float4*)(p + 4);
    union { unsigned short u[8]; bf16x8 v; } r;
    r.u[0] = f2bf(a.x); r.u[1] = f2bf(a.y); r.u[2] = f2bf(a.z); r.u[3] = f2bf(a.w);
    r.u[4] = f2bf(b.x); r.u[5] = f2bf(b.y); r.u[6] = f2bf(b.z); r.u[7] = f2bf(b.w);
    return r.v;
}

// The 16-load h-tile gather; SC = cache-flag string ("sc0" fast / "sc1" slow).
#define HLOAD_BLOCK(SC)                                                     \
    asm volatile(                                                           \
        "global_load_dwordx4 %0,  %16, off offset:-4096 " SC "\n\t"         \
        "global_load_dwordx4 %1,  %16, off " SC "\n\t"                      \
        "global_load_dwordx4 %2,  %17, off offset:-4096 " SC "\n\t"         \
        "global_load_dwordx4 %3,  %17, off " SC "\n\t"                      \
        "global_load_dwordx4 %4,  %18, off offset:-4096 " SC "\n\t"         \
        "global_load_dwordx4 %5,  %18, off " SC "\n\t"                      \
        "global_load_dwordx4 %6,  %19, off offset:-4096 " SC "\n\t"         \
        "global_load_dwordx4 %7,  %19, off " SC "\n\t"                      \
        "global_load_dwordx4 %8,  %20, off offset:-4096 " SC "\n\t"         \
        "global_load_dwordx4 %9,  %20, off " SC "\n\t"                      \
        "global_load_dwordx4 %10, %21, off offset:-4096 " SC "\n\t"         \
        "global_load_dwordx4 %11, %21, off " SC "\n\t"                      \
        "global_load_dwordx4 %12, %22, off offset:-4096 " SC "\n\t"         \
        "global_load_dwordx4 %13, %22, off " SC "\n\t"                      \
        "global_load_dwordx4 %14, %23, off offset:-4096 " SC "\n\t"         \
        "global_load_dwordx4 %15, %23, off " SC "\n\t"                      \
        "s_waitcnt vmcnt(0)"                                                \
        : "=&v"(hv0), "=&v"(hv1), "=&v"(hv2), "=&v"(hv3),                   \
          "=&v"(hv4), "=&v"(hv5), "=&v"(hv6), "=&v"(hv7),                   \
          "=&v"(hv8), "=&v"(hv9), "=&v"(hv10), "=&v"(hv11),                 \
          "=&v"(hv12), "=&v"(hv13), "=&v"(hv14), "=&v"(hv15)                \
        : "v"(b0p), "v"(b1p), "v"(b2p), "v"(b3p),                           \
          "v"(b4p), "v"(b5p), "v"(b6p), "v"(b7p)                            \
        : "memory")

// Persistent LSTM. 256 wgs x 256 threads (1 wg/CU; all co-resident).
// Group g = blockIdx&7 owns batches [g*64, g*64+64); wg r = blockIdx>>3 owns
// hidden units [r*16, r*16+16).
// NEW this round: runtime-verified XCD-local fast path. At startup every wg
// publishes s_getreg(HW_REG_XCC_ID) through the coherent (sc1+L3) path and a
// grid barrier; each group then checks whether all 32 members share one XCD.
// If yes (expected: grp==gid&7 IS the XCD round-robin), the per-step h
// exchange runs entirely in that XCD's shared L2: plain stores (write-through
// to L2), sc0 loads (bypass stale per-CU L1, hit L2), plain global_atomic_add
// flag (executes at L2). The sc1/agent-scope path remains as the verified
// fallback, so correctness never depends on the dispatch mapping.
__global__ __launch_bounds__(256, 1) void lstm_persist(
    const float* __restrict__ X,     const float* __restrict__ W_ih,
    const float* __restrict__ W_hh,  const float* __restrict__ b_ih,
    const float* __restrict__ b_hh,  const float* __restrict__ W_out,
    const float* __restrict__ b_out, float* __restrict__ out,
    unsigned short* __restrict__ hbuf,   // [2][Bd][Hd] bf16 bits (zeroed)
    unsigned int*  __restrict__ bar)     // counters/ids zone, 4096 B (zeroed)
{
    extern __shared__ char smem[];
    unsigned short* htile = (unsigned short*)smem;              // 64*520*2 = 66560 B
    float*          gsum  = (float*)smem;                       // overlays htile
    float*          biasl = (float*)(smem + TG * LDH * 2);
    float*          hpart = biasl + TG;

    const int tid = threadIdx.x;
    const int gid = blockIdx.x;
    const int grp = gid & 7;
    const int r   = gid >> 3;
    const int bb  = grp * BG;
    const int jb  = r * 16;

    // ---- wave/tile constants ----
    const int lane = tid & 63, wid = tid >> 6;
    const int m16  = lane & 15, quad = lane >> 4;
    const int gr0  = (wid & 1) * 32;          // gate-row offset (local)
    const int bt0  = (wid >> 1) * 32;         // batch offset (in group)
    const int brow0 = bb + bt0 + m16;
    const int brow1 = brow0 + 16;
    const unsigned short* hl0 = htile + (bt0 + m16) * LDH + quad * 8;
    const unsigned short* hl1 = hl0 + 16 * LDH;

    // ---- W fragments into registers (one-time) ----
    bf16x8 wh0[16], wh1[16], wx0[4], wx1[4];
    {
        const int lr0 = gr0 + m16, lr1 = lr0 + 16;
        const int gw0 = ((lr0 >> 4) * Hd) + jb + (lr0 & 15);
        const int gw1 = ((lr1 >> 4) * Hd) + jb + (lr1 & 15);
        const float* ph0 = W_hh + (size_t)gw0 * Hd + quad * 8;
        const float* ph1 = W_hh + (size_t)gw1 * Hd + quad * 8;
        const float* px0 = W_ih + (size_t)gw0 * Fd + quad * 8;
        const float* px1 = W_ih + (size_t)gw1 * Fd + quad * 8;
#pragma unroll
        for (int ks = 0; ks < 16; ++ks) {
            wh0[ks] = pack8(ph0 + ks * 32);
            wh1[ks] = pack8(ph1 + ks * 32);
        }
#pragma unroll
        for (int ks = 0; ks < 4; ++ks) {
            wx0[ks] = pack8(px0 + ks * 32);
            wx1[ks] = pack8(px1 + ks * 32);
        }
    }
    if (tid < TG) {
        int grow = ((tid >> 4) * Hd) + jb + (tid & 15);
        biasl[tid] = b_ih[grow] + b_hh[grow];
    }

    // ---- startup: verify the group is XCD-local (coherent path + grid bar) ----
    unsigned myxcd;
    asm volatile("s_getreg_b32 %0, hwreg(HW_REG_XCC_ID)" : "=s"(myxcd));
    if (tid == 0) {
        unsigned int* xcdid = bar + 256;   // bytes 1024.. (within zeroed 4 KB)
        unsigned int* ready = bar + 240;   // own 64B line, clear of grp counters
        asm volatile("global_store_dword %0, %1, off sc1\n\ts_waitcnt vmcnt(0)"
                     :: "v"(xcdid + gid), "v"(myxcd) : "memory");
        __hip_atomic_fetch_add(ready, 1u, __ATOMIC_RELAXED, __HIP_MEMORY_SCOPE_AGENT);
        while (__hip_atomic_load(ready, __ATOMIC_RELAXED, __HIP_MEMORY_SCOPE_AGENT) < 256u)
            __builtin_amdgcn_s_sleep(4);
        unsigned ok = 1;
        for (int j = 0; j < WPG; ++j) {
            unsigned v;
            asm volatile("global_load_dword %0, %1, off sc1\n\ts_waitcnt vmcnt(0)"
                         : "=v"(v) : "v"(xcdid + (grp + 8 * j)) : "memory");
            ok &= (v == myxcd) ? 1u : 0u;
        }
        ((unsigned*)hpart)[0] = ok;
    }
    __syncthreads();
    const bool fast = ((const unsigned*)hpart)[0] != 0;
    // (hpart[0] is consumed by all threads here; next write to hpart is after
    //  several barriers inside step 0, so no extra barrier needed.)

    // elementwise mapping
    const int eb  = tid & 63;
    const int jjb = (tid >> 6) << 2;
    float wout[4];
#pragma unroll
    for (int u = 0; u < 4; ++u) wout[u] = W_out[jb + jjb + u];
    const float bo = b_out[0];
    float cst[4] = {0.f, 0.f, 0.f, 0.f};

    unsigned int* mybar = bar + grp * 32;
    unsigned short* hw_lds = htile + (size_t)(tid >> 6) * LDH + (tid & 63) * 8;

    f32x4 acc00, acc01, acc10, acc11;
    const float* xp0 = X + (size_t)brow0 * (Td * Fd) + quad * 8;
    const float* xp1 = X + (size_t)brow1 * (Td * Fd) + quad * 8;

    // x-projection MFMAs for one timestep (reads current xp0/xp1)
    auto do_xpart = [&]() {
#pragma unroll
        for (int ks = 0; ks < 4; ++ks) {
            float4 xa = *(const float4*)(xp0 + ks * 32);
            float4 xb = *(const float4*)(xp0 + ks * 32 + 4);
            float4 ya = *(const float4*)(xp1 + ks * 32);
            float4 yb = *(const float4*)(xp1 + ks * 32 + 4);
            bf16x8 b0, b1;
            b0[0]=(__bf16)xa.x; b0[1]=(__bf16)xa.y; b0[2]=(__bf16)xa.z; b0[3]=(__bf16)xa.w;
            b0[4]=(__bf16)xb.x; b0[5]=(__bf16)xb.y; b0[6]=(__bf16)xb.z; b0[7]=(__bf16)xb.w;
            b1[0]=(__bf16)ya.x; b1[1]=(__bf16)ya.y; b1[2]=(__bf16)ya.z; b1[3]=(__bf16)ya.w;
            b1[4]=(__bf16)yb.x; b1[5]=(__bf16)yb.y; b1[6]=(__bf16)yb.z; b1[7]=(__bf16)yb.w;
            acc00 = __builtin_amdgcn_mfma_f32_16x16x32_bf16(wx0[ks], b0, acc00, 0, 0, 0);
            acc01 = __builtin_amdgcn_mfma_f32_16x16x32_bf16(wx0[ks], b1, acc01, 0, 0, 0);
            acc10 = __builtin_amdgcn_mfma_f32_16x16x32_bf16(wx1[ks], b0, acc10, 0, 0, 0);
            acc11 = __builtin_amdgcn_mfma_f32_16x16x32_bf16(wx1[ks], b1, acc11, 0, 0, 0);
        }
    };

    // prologue: x-part for t=0
    acc00 = f32x4{0.f,0.f,0.f,0.f}; acc01 = f32x4{0.f,0.f,0.f,0.f};
    acc10 = f32x4{0.f,0.f,0.f,0.f}; acc11 = f32x4{0.f,0.f,0.f,0.f};
    do_xpart();

    for (int t = 0; t < Td; ++t) {
        // ---- poll: all wgs have stored h(t-1) ----
        if (t > 0 && tid == 0) {
            unsigned tgt = (unsigned)t * WPG;
            if (fast) {
                // L2-local spin: plain-atomic counter lives in this XCD's L2
                for (;;) {
                    unsigned v;
                    asm volatile("global_load_dword %0, %1, off sc0\n\t"
                                 "s_waitcnt vmcnt(0)"
                                 : "=v"(v) : "v"(mybar) : "memory");
                    if (v >= tgt) break;
                }
            } else {
                while (__hip_atomic_load(mybar, __ATOMIC_RELAXED, __HIP_MEMORY_SCOPE_AGENT) < tgt)
                    __builtin_amdgcn_s_sleep(2);
            }
        }
        __syncthreads();                                   // A: flag seen; gsum/hpart free

        const unsigned short* hprev = hbuf + (size_t)((t & 1) ^ 1) * (Bd * Hd);

        // ---- load group h tile (64 KB) and stage to LDS ----
        u32x4 hv0,hv1,hv2,hv3,hv4,hv5,hv6,hv7,hv8,hv9,hv10,hv11,hv12,hv13,hv14,hv15;
        {
            const unsigned short* p0 =
                hprev + (size_t)(bb + (tid >> 6)) * Hd + (tid & 63) * 8;
            const unsigned short* b0p = p0 + 1 * 2048;
            const unsigned short* b1p = p0 + 3 * 2048;
            const unsigned short* b2p = p0 + 5 * 2048;
            const unsigned short* b3p = p0 + 7 * 2048;
            const unsigned short* b4p = p0 + 9 * 2048;
            const unsigned short* b5p = p0 + 11 * 2048;
            const unsigned short* b6p = p0 + 13 * 2048;
            const unsigned short* b7p = p0 + 15 * 2048;
            if (fast) { HLOAD_BLOCK("sc0"); } else { HLOAD_BLOCK("sc1"); }
        }
        *(u32x4*)(hw_lds + 0 * 2080)  = hv0;  *(u32x4*)(hw_lds + 1 * 2080)  = hv1;
        *(u32x4*)(hw_lds + 2 * 2080)  = hv2;  *(u32x4*)(hw_lds + 3 * 2080)  = hv3;
        *(u32x4*)(hw_lds + 4 * 2080)  = hv4;  *(u32x4*)(hw_lds + 5 * 2080)  = hv5;
        *(u32x4*)(hw_lds + 6 * 2080)  = hv6;  *(u32x4*)(hw_lds + 7 * 2080)  = hv7;
        *(u32x4*)(hw_lds + 8 * 2080)  = hv8;  *(u32x4*)(hw_lds + 9 * 2080)  = hv9;
        *(u32x4*)(hw_lds + 10 * 2080) = hv10; *(u32x4*)(hw_lds + 11 * 2080) = hv11;
        *(u32x4*)(hw_lds + 12 * 2080) = hv12; *(u32x4*)(hw_lds + 13 * 2080) = hv13;
        *(u32x4*)(hw_lds + 14 * 2080) = hv14; *(u32x4*)(hw_lds + 15 * 2080) = hv15;
        __syncthreads();                                   // B: htile ready

        // ---- h part (K = 0..511): A from registers, B from LDS ----
#pragma unroll
        for (int ks = 0; ks < 16; ++ks) {
            bf16x8 b0 = *(const bf16x8*)(hl0 + ks * 32);
            bf16x8 b1 = *(const bf16x8*)(hl1 + ks * 32);
            acc00 = __builtin_amdgcn_mfma_f32_16x16x32_bf16(wh0[ks], b0, acc00, 0, 0, 0);
            acc01 = __builtin_amdgcn_mfma_f32_16x16x32_bf16(wh0[ks], b1, acc01, 0, 0, 0);
            acc10 = __builtin_amdgcn_mfma_f32_16x16x32_bf16(wh1[ks], b0, acc10, 0, 0, 0);
            acc11 = __builtin_amdgcn_mfma_f32_16x16x32_bf16(wh1[ks], b1, acc11, 0, 0, 0);
        }
        __syncthreads();                                   // C: htile free

        // ---- gate preacts to LDS (C-layout: row = quad*4+v, col = lane&15) ----
        {
            const int row = gr0 + (quad << 2);
            const int col = bt0 + m16;
            float* g00 = gsum + row * LDG + col;
            float* g10 = gsum + (row + 16) * LDG + col;
#pragma unroll
            for (int v = 0; v < 4; ++v) {
                g00[v * LDG]      = acc00[v];
                g00[v * LDG + 16] = acc01[v];
                g10[v * LDG]      = acc10[v];
                g10[v * LDG + 16] = acc11[v];
            }
        }
        __syncthreads();                                   // D: gsum ready

        // ---- gate math; c in regs; h -> global ----
        float part = 0.f;
        unsigned short hvb[4];
#pragma unroll
        for (int u = 0; u < 4; ++u) {
            int jj = jjb + u;
            float pi = gsum[jj * LDG + eb]        + biasl[jj];
            float pf = gsum[(16 + jj) * LDG + eb] + biasl[16 + jj];
            float pg = gsum[(32 + jj) * LDG + eb] + biasl[32 + jj];
            float po = gsum[(48 + jj) * LDG + eb] + biasl[48 + jj];
            float ii = sigm(pi), ff = sigm(pf);
            float gg = tanh_fast(pg), oo = sigm(po);
            float c  = ff * cst[u] + ii * gg;
            cst[u]   = c;
            float h  = oo * tanh_fast(c);
            hvb[u]   = f2bf(h);
            part    += h * wout[u];
        }
        {
            u32x2 hd2;
            hd2[0] = (unsigned)hvb[0] | ((unsigned)hvb[1] << 16);
            hd2[1] = (unsigned)hvb[2] | ((unsigned)hvb[3] << 16);
            unsigned short* hwp =
                hbuf + (size_t)(t & 1) * (Bd * Hd) + (size_t)(bb + eb) * Hd + jb + jjb;
            if (fast) {
                // plain store: write-through to this XCD's L2 (no L3 force)
                asm volatile("global_store_dwordx2 %0, %1, off"
                             :: "v"(hwp), "v"(hd2) : "memory");
            } else {
                asm volatile("global_store_dwordx2 %0, %1, off sc1"
                             :: "v"(hwp), "v"(hd2) : "memory");
            }
            asm volatile("s_waitcnt vmcnt(0)" ::: "memory");  // durable at L2/L3
        }
        // ---- flag ----
        if (tid == 0) {
            if (fast) {
                unsigned one = 1u;
                asm volatile("global_atomic_add %0, %1, off"
                             :: "v"(mybar), "v"(one) : "memory");
            } else {
                __hip_atomic_fetch_add(mybar, 1u, __ATOMIC_RELAXED, __HIP_MEMORY_SCOPE_AGENT);
            }
        }

        hpart[tid] = part;

        // ---- overlap barrier skew: x-part for t+1 ----
        acc00 = f32x4{0.f,0.f,0.f,0.f}; acc01 = f32x4{0.f,0.f,0.f,0.f};
        acc10 = f32x4{0.f,0.f,0.f,0.f}; acc11 = f32x4{0.f,0.f,0.f,0.f};
        if (t + 1 < Td) {
            xp0 += Fd; xp1 += Fd;
            do_xpart();
        }

        __syncthreads();                                   // E: hpart ready
        if (tid < 64) {
            float s = hpart[tid] + hpart[tid + 64] + hpart[tid + 128] + hpart[tid + 192];
            if (r == 0) s += bo;
            atomicAdd(out + (size_t)(bb + tid) * Td + t, s);
        }
    }
}

extern "C" void kernel_launch(void* const* d_in, const int* in_sizes, int n_in,
                              void* d_out, int out_size, void* d_ws, size_t ws_size,
                              hipStream_t stream) {
    const float* X     = (const float*)d_in[0];
    const float* W_ih  = (const float*)d_in[1];
    const float* W_hh  = (const float*)d_in[2];
    const float* b_ih  = (const float*)d_in[3];
    const float* b_hh  = (const float*)d_in[4];
    const float* W_out = (const float*)d_in[5];
    const float* b_out = (const float*)d_in[6];
    float* out = (float*)d_out;

    unsigned short* hbuf = (unsigned short*)d_ws;                 // 2*Bd*Hd bf16 = 1 MiB
    unsigned int*   bar  = (unsigned int*)((char*)d_ws + 2u * Bd * Hd * 2u);

    hipMemsetAsync(d_ws, 0, 2u * Bd * Hd * 2u + 4096u, stream);
    hipMemsetAsync(d_out, 0, (size_t)out_size * sizeof(float), stream);

    const size_t smem = (size_t)TG * LDH * 2      // htile/gsum    66560
                      + TG * 4 + 256 * 4;         // bias + hpart   1280  => 67840
    (void)hipFuncSetAttribute((const void*)lstm_persist,
                              hipFuncAttributeMaxDynamicSharedMemorySize, (int)smem);

    lstm_persist<<<dim3(256), dim3(256), smem, stream>>>(
        X, W_ih, W_hh, b_ih, b_hh, W_out, b_out, out, hbuf, bar);
}